// Round 1
// baseline (312.312 us; speedup 1.0000x reference)
//
#include <hip/hip_runtime.h>

#define BETA   0.1f
#define MARGIN 0.1f
#define EPSF   1e-6f
#define KNEG   4

__device__ __forceinline__ float gsum16(float v) {
    #pragma unroll
    for (int off = 8; off >= 1; off >>= 1) v += __shfl_xor(v, off, 64);
    return v;
}
__device__ __forceinline__ int gsum16i(int v) {
    #pragma unroll
    for (int off = 8; off >= 1; off >>= 1) v += __shfl_xor(v, off, 64);
    return v;
}
__device__ __forceinline__ float gmax16(float v) {
    #pragma unroll
    for (int off = 8; off >= 1; off >>= 1) v = fmaxf(v, __shfl_xor(v, off, 64));
    return v;
}
__device__ __forceinline__ float wave_sum(float v) {
    #pragma unroll
    for (int off = 32; off >= 1; off >>= 1) v += __shfl_xor(v, off, 64);
    return v;
}
__device__ __forceinline__ float dot4(float4 a, float4 b) {
    return a.x*b.x + a.y*b.y + a.z*b.z + a.w*b.w;
}

// ---- pass 1: SIGNED int4 table (128 B/row) + side {norm2, aperture, scale} ----
// Element->nibble mapping is PERMUTED for coalescing: lane sl packs float4s
// {sl, sl+16, sl+32, sl+48} of the row. Dots and norms are permutation-
// invariant as long as every row uses the same mapping (it does).
// Also zero-inits the 16 B accumulator block used by the fused reduction
// (ws is re-poisoned every iteration, so the zeroing must be in-graph).
__global__ __launch_bounds__(256) void cvt_i4(
    const float* __restrict__ in, uint2* __restrict__ tab,
    float4* __restrict__ side, float* __restrict__ acc, int C)
{
    if (blockIdx.x == 0 && threadIdx.x == 0) {
        acc[0] = 0.f;                    // pos sum
        acc[1] = 0.f;                    // neg sum
        ((unsigned*)acc)[2] = 0u;        // block-completion counter
    }
    const int sl  = threadIdx.x & 15;
    const int row = (blockIdx.x * 256 + threadIdx.x) >> 4;
    if (row >= C) return;
    const float4* src = (const float4*)(in + (size_t)row * 256);
    // per-instruction fully coalesced: 16 lanes x 16 B contiguous = 256 B/instr
    float4 v0 = src[sl +  0], v1 = src[sl + 16], v2 = src[sl + 32], v3 = src[sl + 48];
    float f[16] = { v0.x, v0.y, v0.z, v0.w,  v1.x, v1.y, v1.z, v1.w,
                    v2.x, v2.y, v2.z, v2.w,  v3.x, v3.y, v3.z, v3.w };
    float am = 0.f;
    #pragma unroll
    for (int d = 0; d < 16; ++d) am = fmaxf(am, fabsf(f[d]));
    am = gmax16(am);
    const float inv = (am > 0.f) ? (7.0f / am) : 0.f;
    unsigned u0 = 0, u1 = 0;
    #pragma unroll
    for (int n = 0; n < 8; ++n) {
        int c = (int)rintf(f[n] * inv);
        c = (c < -8) ? -8 : ((c > 7) ? 7 : c);
        u0 |= ((unsigned)c & 0xFu) << (4 * n);      // two's-complement nibble
    }
    #pragma unroll
    for (int n = 0; n < 8; ++n) {
        int c = (int)rintf(f[8 + n] * inv);
        c = (c < -8) ? -8 : ((c > 7) ? 7 : c);
        u1 |= ((unsigned)c & 0xFu) << (4 * n);
    }
    tab[(size_t)row * 16 + sl] = make_uint2(u0, u1);
    float ss = gsum16(dot4(v0,v0) + dot4(v1,v1) + dot4(v2,v2) + dot4(v3,v3));
    if (sl == 0) {
        float np = sqrtf(ss);
        float ap = asinf(fminf(fmaxf(BETA / (np + EPSF), 0.f), 1.f - EPSF));
        side[row] = make_float4(ss, ap, am * (1.f / 7.0f), 0.f);
    }
}

// Signed-nibble dot of 16 elems/lane: 2 x v_dot8_i32_i4 if available.
__device__ __forceinline__ int nib_dot(uint2 a, uint2 b) {
#if __has_builtin(__builtin_amdgcn_sdot8)
    int d = __builtin_amdgcn_sdot8((int)a.x, (int)b.x, 0, false);
    return  __builtin_amdgcn_sdot8((int)a.y, (int)b.y, d, false);
#else
    int acc = 0;
    #pragma unroll
    for (int n = 0; n < 8; ++n) {
        int pa = ((int)(a.x << (28 - 4*n))) >> 28;
        int pb = ((int)(b.x << (28 - 4*n))) >> 28;
        acc += pa * pb;
    }
    #pragma unroll
    for (int n = 0; n < 8; ++n) {
        int pa = ((int)(a.y << (28 - 4*n))) >> 28;
        int pb = ((int)(b.y << (28 - 4*n))) >> 28;
        acc += pa * pb;
    }
    return acc;
#endif
}

// ---- pass 2 (fused with final reduction): gather + energy.
// sdot8 integer dots (exact vs the quantized table); the wave's 20 acos args
// are lane-parked and evaluated with ONE wave-wide acosf. Block partials go
// through device-scope atomics; the last block to finish writes the output.
__global__ __launch_bounds__(256) void cone_main_i4(
    const uint2*  __restrict__ tab,
    const float4* __restrict__ side,
    const int*    __restrict__ pairs,
    const int*    __restrict__ negc,
    float*        __restrict__ acc,
    float*        __restrict__ out,
    int P)
{
    const int lane = threadIdx.x & 63;
    const int wid  = threadIdx.x >> 6;
    const int sub  = lane >> 4;
    const int sl   = lane & 15;
    const int pair = (blockIdx.x * 4 + wid) * 4 + sub;

    float pos_e = 0.f, neg_e = 0.f;
    if (pair < P) {
        const int pi = pairs[2 * pair];
        const int i0 = pairs[2 * pair + 1];
        const int i1 = negc[4 * pair + 0];
        const int i2 = negc[4 * pair + 1];
        const int i3 = negc[4 * pair + 2];
        const int i4 = negc[4 * pair + 3];

        // Issue ALL loads (6 rows + side) before compute.
        uint2 pu  = tab[(size_t)pi * 16 + sl];
        uint2 cu0 = tab[(size_t)i0 * 16 + sl];
        uint2 cu1 = tab[(size_t)i1 * 16 + sl];
        uint2 cu2 = tab[(size_t)i2 * 16 + sl];
        uint2 cu3 = tab[(size_t)i3 * 16 + sl];
        uint2 cu4 = tab[(size_t)i4 * 16 + sl];

        int tidx = pi;
        tidx = (sl == 1) ? i0 : tidx;
        tidx = (sl == 2) ? i1 : tidx;
        tidx = (sl == 3) ? i2 : tidx;
        tidx = (sl == 4) ? i3 : tidx;
        tidx = (sl == 5) ? i4 : tidx;
        float4 sd = side[tidx];

        const int base = sub * 16;
        const float p2 = __shfl(sd.x, base + 0, 64);
        const float ap = __shfl(sd.y, base + 0, 64);
        const float sp = __shfl(sd.z, base + 0, 64);
        const float np = sqrtf(p2);

        float my_ca = 1.f;   // park acos args; acos(1)=0 on idle lanes

#define CONE_STEP(J, CU)                                                      \
        {                                                                     \
            const float draw = (float)gsum16i(nib_dot(pu, CU));               \
            const float c2 = __shfl(sd.x, base + 1 + J, 64);                  \
            const float sc = __shfl(sd.z, base + 1 + J, 64);                  \
            const float dot = draw * sp * sc;                                 \
            const float num = 2.f * (dot - p2);                               \
            const float d2  = fmaxf(c2 + p2 - 2.f * dot, 0.f);                \
            const float den = 2.f * np * sqrtf(d2) + EPSF;                    \
            const float ca  = fminf(fmaxf(num / den, -1.f + EPSF), 1.f - EPSF);\
            my_ca = (sl == J) ? ca : my_ca;                                   \
        }
        CONE_STEP(0, cu0)
        CONE_STEP(1, cu1)
        CONE_STEP(2, cu2)
        CONE_STEP(3, cu3)
        CONE_STEP(4, cu4)
#undef CONE_STEP

        // ONE wave-wide acos covers all 20 parked values (4 pairs x 5).
        const float ang = acosf(my_ca);
        const float e   = fmaxf(ang - ap, 0.f);
        pos_e = (sl == 0) ? e : 0.f;
        const float neg_c = (sl >= 1 && sl <= 4) ? fmaxf(MARGIN - e, 0.f) : 0.f;
        neg_e = gsum16(neg_c);
    }

    __shared__ float spos[16], sneg[16];
    if (sl == 0) { spos[wid * 4 + sub] = pos_e; sneg[wid * 4 + sub] = neg_e; }
    __syncthreads();
    if (threadIdx.x == 0) {
        float ps = 0.f, ns = 0.f;
        #pragma unroll
        for (int i = 0; i < 16; ++i) { ps += spos[i]; ns += sneg[i]; }
        atomicAdd(&acc[0], ps);
        atomicAdd(&acc[1], ns);
        __threadfence();
        const unsigned prev = atomicAdd((unsigned*)&acc[2], 1u);
        if (prev == gridDim.x - 1) {
            // All contributions are globally visible: every block fenced
            // before its counter increment. Read back via device-scope RMW.
            const float tp = atomicAdd(&acc[0], 0.f);
            const float tn = atomicAdd(&acc[1], 0.f);
            const float fP = (float)P;
            out[0] = (tp / fP + tn / (fP * (float)KNEG)) * 0.5f;
        }
    }
}

// ---- fp32 fallback (R2 kernel) if ws can't hold the tables ----
__global__ __launch_bounds__(256) void cone_main_f32(
    const float* __restrict__ proto,
    const int*   __restrict__ pairs,
    const int*   __restrict__ negc,
    float*       __restrict__ part,
    int P)
{
    const int lane = threadIdx.x & 63;
    const int wid  = threadIdx.x >> 6;
    const int sub  = lane >> 4;
    const int sl   = lane & 15;
    const int pair = (blockIdx.x * 4 + wid) * 4 + sub;

    float pos_e = 0.f, neg_e = 0.f;
    if (pair < P) {
        const int pi = pairs[2 * pair];
        const int i0 = pairs[2 * pair + 1];
        const int i1 = negc[4 * pair + 0];
        const int i2 = negc[4 * pair + 1];
        const int i3 = negc[4 * pair + 2];
        const int i4 = negc[4 * pair + 3];

        const float4* prow = (const float4*)(proto + (size_t)pi * 256);
        float4 pv[4];
        #pragma unroll
        for (int r = 0; r < 4; ++r) pv[r] = prow[sl + 16 * r];

        float pp = 0.f;
        #pragma unroll
        for (int r = 0; r < 4; ++r) pp += dot4(pv[r], pv[r]);
        float p2     = gsum16(pp);
        float norm_p = sqrtf(p2);
        float apert  = asinf(fminf(fmaxf(BETA / (norm_p + EPSF), 0.f), 1.f - EPSF));

#define CONE_F32_STEP(J, IDX)                                                 \
        {                                                                     \
            const float4* crow = (const float4*)(proto + (size_t)(IDX) * 256);\
            float cc = 0.f, dd = 0.f;                                         \
            _Pragma("unroll")                                                 \
            for (int r = 0; r < 4; ++r) {                                     \
                float4 c = crow[sl + 16 * r], p = pv[r];                      \
                cc += dot4(c, c);                                             \
                float dx = c.x-p.x, dy = c.y-p.y, dz = c.z-p.z, dw = c.w-p.w; \
                dd += dx*dx + dy*dy + dz*dz + dw*dw;                          \
            }                                                                 \
            float c2 = gsum16(cc);                                            \
            float d2 = gsum16(dd);                                            \
            float num    = c2 - p2 - d2;                                      \
            float den    = 2.f * norm_p * sqrtf(d2) + EPSF;                   \
            float cosang = fminf(fmaxf(num / den, -1.f + EPSF), 1.f - EPSF);  \
            float e      = fmaxf(acosf(cosang) - apert, 0.f);                 \
            if (J == 0) pos_e = e;                                            \
            else        neg_e += fmaxf(MARGIN - e, 0.f);                      \
        }
        CONE_F32_STEP(0, i0)
        CONE_F32_STEP(1, i1)
        CONE_F32_STEP(2, i2)
        CONE_F32_STEP(3, i3)
        CONE_F32_STEP(4, i4)
#undef CONE_F32_STEP
    }

    __shared__ float sp[16], sn[16];
    if (sl == 0) { sp[wid * 4 + sub] = pos_e; sn[wid * 4 + sub] = neg_e; }
    __syncthreads();
    if (threadIdx.x == 0) {
        float ps = 0.f, ns = 0.f;
        #pragma unroll
        for (int i = 0; i < 16; ++i) { ps += sp[i]; ns += sn[i]; }
        part[2 * blockIdx.x]     = ps;
        part[2 * blockIdx.x + 1] = ns;
    }
}

__global__ __launch_bounds__(1024) void cone_final(
    const float* __restrict__ part, float* __restrict__ out, int nblocks, int P)
{
    float ps = 0.f, ns = 0.f;
    for (int i = threadIdx.x; i < nblocks; i += 1024) {
        ps += part[2 * i];
        ns += part[2 * i + 1];
    }
    ps = wave_sum(ps);
    ns = wave_sum(ns);
    const int lane = threadIdx.x & 63, wid = threadIdx.x >> 6;
    __shared__ float sp[16], sn[16];
    if (lane == 0) { sp[wid] = ps; sn[wid] = ns; }
    __syncthreads();
    if (threadIdx.x == 0) {
        float tp = 0.f, tn = 0.f;
        #pragma unroll
        for (int i = 0; i < 16; ++i) { tp += sp[i]; tn += sn[i]; }
        float fP = (float)P;
        out[0] = (tp / fP + tn / (fP * (float)KNEG)) * 0.5f;
    }
}

extern "C" void kernel_launch(void* const* d_in, const int* in_sizes, int n_in,
                              void* d_out, int out_size, void* d_ws, size_t ws_size,
                              hipStream_t stream) {
    const float* proto = (const float*)d_in[0];
    const int*   pairs = (const int*)d_in[1];
    const int*   negc  = (const int*)d_in[2];
    const int P = in_sizes[1] / 2;
    const int C = in_sizes[0] / 256;
    const int nblocks = (P + 15) / 16;

    const size_t tab_bytes  = (size_t)C * 128;
    const size_t side_bytes = (size_t)C * 16;
    const size_t acc_bytes  = 16;
    const size_t need = tab_bytes + side_bytes + acc_bytes;

    if (ws_size >= need) {
        char* base = (char*)d_ws;
        uint2*  tab  = (uint2*)base;
        float4* side = (float4*)(base + tab_bytes);
        float*  acc  = (float*)(base + tab_bytes + side_bytes);

        cvt_i4<<<(C + 15) / 16, 256, 0, stream>>>(proto, tab, side, acc, C);
        cone_main_i4<<<nblocks, 256, 0, stream>>>(tab, side, pairs, negc, acc,
                                                  (float*)d_out, P);
    } else {
        float* part = (float*)d_ws;
        cone_main_f32<<<nblocks, 256, 0, stream>>>(proto, pairs, negc, part, P);
        cone_final<<<1, 1024, 0, stream>>>(part, (float*)d_out, nblocks, P);
    }
}

// Round 2
// 168.244 us; speedup vs baseline: 1.8563x; 1.8563x over previous
//
#include <hip/hip_runtime.h>

#define BETA   0.1f
#define MARGIN 0.1f
#define EPSF   1e-6f
#define KNEG   4

__device__ __forceinline__ float gsum16(float v) {
    #pragma unroll
    for (int off = 8; off >= 1; off >>= 1) v += __shfl_xor(v, off, 64);
    return v;
}
__device__ __forceinline__ int gsum16i(int v) {
    #pragma unroll
    for (int off = 8; off >= 1; off >>= 1) v += __shfl_xor(v, off, 64);
    return v;
}
__device__ __forceinline__ float gmax16(float v) {
    #pragma unroll
    for (int off = 8; off >= 1; off >>= 1) v = fmaxf(v, __shfl_xor(v, off, 64));
    return v;
}
__device__ __forceinline__ float wave_sum(float v) {
    #pragma unroll
    for (int off = 32; off >= 1; off >>= 1) v += __shfl_xor(v, off, 64);
    return v;
}
__device__ __forceinline__ float dot4(float4 a, float4 b) {
    return a.x*b.x + a.y*b.y + a.z*b.z + a.w*b.w;
}

// ---- pass 1: SIGNED int4 table (128 B/row) + side {norm2, aperture, scale} ----
// Element->nibble mapping is PERMUTED for coalescing: lane sl packs float4s
// {sl, sl+16, sl+32, sl+48} of the row (per-instruction contiguous 256 B per
// 16-lane group). Dots/norms are permutation-invariant since every row uses
// the same mapping.
__global__ __launch_bounds__(256) void cvt_i4(
    const float* __restrict__ in, uint2* __restrict__ tab,
    float4* __restrict__ side, int C)
{
    const int sl  = threadIdx.x & 15;
    const int row = (blockIdx.x * 256 + threadIdx.x) >> 4;
    if (row >= C) return;
    const float4* src = (const float4*)(in + (size_t)row * 256);
    float4 v0 = src[sl +  0], v1 = src[sl + 16], v2 = src[sl + 32], v3 = src[sl + 48];
    float f[16] = { v0.x, v0.y, v0.z, v0.w,  v1.x, v1.y, v1.z, v1.w,
                    v2.x, v2.y, v2.z, v2.w,  v3.x, v3.y, v3.z, v3.w };
    float am = 0.f;
    #pragma unroll
    for (int d = 0; d < 16; ++d) am = fmaxf(am, fabsf(f[d]));
    am = gmax16(am);
    const float inv = (am > 0.f) ? (7.0f / am) : 0.f;
    unsigned u0 = 0, u1 = 0;
    #pragma unroll
    for (int n = 0; n < 8; ++n) {
        int c = (int)rintf(f[n] * inv);
        c = (c < -8) ? -8 : ((c > 7) ? 7 : c);
        u0 |= ((unsigned)c & 0xFu) << (4 * n);      // two's-complement nibble
    }
    #pragma unroll
    for (int n = 0; n < 8; ++n) {
        int c = (int)rintf(f[8 + n] * inv);
        c = (c < -8) ? -8 : ((c > 7) ? 7 : c);
        u1 |= ((unsigned)c & 0xFu) << (4 * n);
    }
    tab[(size_t)row * 16 + sl] = make_uint2(u0, u1);
    float ss = gsum16(dot4(v0,v0) + dot4(v1,v1) + dot4(v2,v2) + dot4(v3,v3));
    if (sl == 0) {
        float np = sqrtf(ss);
        float ap = asinf(fminf(fmaxf(BETA / (np + EPSF), 0.f), 1.f - EPSF));
        side[row] = make_float4(ss, ap, am * (1.f / 7.0f), 0.f);
    }
}

// Signed-nibble dot of 16 elems/lane: 2 x v_dot8_i32_i4 if available.
__device__ __forceinline__ int nib_dot(uint2 a, uint2 b) {
#if __has_builtin(__builtin_amdgcn_sdot8)
    int d = __builtin_amdgcn_sdot8((int)a.x, (int)b.x, 0, false);
    return  __builtin_amdgcn_sdot8((int)a.y, (int)b.y, d, false);
#else
    int acc = 0;
    #pragma unroll
    for (int n = 0; n < 8; ++n) {
        int pa = ((int)(a.x << (28 - 4*n))) >> 28;
        int pb = ((int)(b.x << (28 - 4*n))) >> 28;
        acc += pa * pb;
    }
    #pragma unroll
    for (int n = 0; n < 8; ++n) {
        int pa = ((int)(a.y << (28 - 4*n))) >> 28;
        int pb = ((int)(b.y << (28 - 4*n))) >> 28;
        acc += pa * pb;
    }
    return acc;
#endif
}

// ---- pass 2: gather + energy, TWO pairs per 16-lane group (ILP x2 on the
// latency-bound gathers: 12 row loads + 1 side load + 3 int4 index loads all
// in flight before compute). Pair A parks acos args on lanes 0-4, pair B on
// lanes 8-12; ONE wave-wide acosf covers all 40 parked values (16 groups x ...
// per wave: 8 pairs x 5). Block partials go to part[]; cone_final reduces.
__global__ __launch_bounds__(256) void cone_main_i4(
    const uint2*  __restrict__ tab,
    const float4* __restrict__ side,
    const int*    __restrict__ pairs,
    const int*    __restrict__ negc,
    float*        __restrict__ part,
    int P)
{
    const int lane = threadIdx.x & 63;
    const int wid  = threadIdx.x >> 6;
    const int sub  = lane >> 4;
    const int sl   = lane & 15;
    const int g    = (blockIdx.x * 4 + wid) * 4 + sub;   // group id
    const int pairA = 2 * g;
    const int pairB = 2 * g + 1;

    float pos_e = 0.f, neg_e = 0.f;
    if (pairA < P) {
        const bool validB = (pairB < P);

        int piA, c0A, piB, c0B;
        int4 nA, nB;
        if (validB) {
            const int4 pp = ((const int4*)pairs)[g];     // {pA.p, pA.c, pB.p, pB.c}
            piA = pp.x; c0A = pp.y; piB = pp.z; c0B = pp.w;
            nA = ((const int4*)negc)[2 * g + 0];
            nB = ((const int4*)negc)[2 * g + 1];
        } else {
            piA = pairs[2 * pairA]; c0A = pairs[2 * pairA + 1];
            nA  = ((const int4*)negc)[2 * g + 0];
            piB = piA; c0B = c0A; nB = nA;               // masked out below
        }

        // Issue ALL table loads (12 rows) before compute.
        uint2 puA  = tab[(size_t)piA  * 16 + sl];
        uint2 cuA0 = tab[(size_t)c0A  * 16 + sl];
        uint2 cuA1 = tab[(size_t)nA.x * 16 + sl];
        uint2 cuA2 = tab[(size_t)nA.y * 16 + sl];
        uint2 cuA3 = tab[(size_t)nA.z * 16 + sl];
        uint2 cuA4 = tab[(size_t)nA.w * 16 + sl];
        uint2 puB  = tab[(size_t)piB  * 16 + sl];
        uint2 cuB0 = tab[(size_t)c0B  * 16 + sl];
        uint2 cuB1 = tab[(size_t)nB.x * 16 + sl];
        uint2 cuB2 = tab[(size_t)nB.y * 16 + sl];
        uint2 cuB3 = tab[(size_t)nB.z * 16 + sl];
        uint2 cuB4 = tab[(size_t)nB.w * 16 + sl];

        // Side gather: lanes 0-5 -> pair A {p, c0..c4}, lanes 8-13 -> pair B.
        int tidx = piA;
        tidx = (sl == 1)  ? c0A  : tidx;
        tidx = (sl == 2)  ? nA.x : tidx;
        tidx = (sl == 3)  ? nA.y : tidx;
        tidx = (sl == 4)  ? nA.z : tidx;
        tidx = (sl == 5)  ? nA.w : tidx;
        tidx = (sl == 8)  ? piB  : tidx;
        tidx = (sl == 9)  ? c0B  : tidx;
        tidx = (sl == 10) ? nB.x : tidx;
        tidx = (sl == 11) ? nB.y : tidx;
        tidx = (sl == 12) ? nB.z : tidx;
        tidx = (sl == 13) ? nB.w : tidx;
        float4 sd = side[tidx];

        const int base = sub * 16;
        const float p2A = __shfl(sd.x, base + 0, 64);
        const float apA = __shfl(sd.y, base + 0, 64);
        const float spA = __shfl(sd.z, base + 0, 64);
        const float npA = sqrtf(p2A);
        const float p2B = __shfl(sd.x, base + 8, 64);
        const float apB = __shfl(sd.y, base + 8, 64);
        const float spB = __shfl(sd.z, base + 8, 64);
        const float npB = sqrtf(p2B);

        float my_ca = 1.f;   // park acos args; acos(1)=0 on idle lanes

#define CONE_STEP(PARKSL, SIDESL, PU, CU, P2, SP, NP)                          \
        {                                                                      \
            const float draw = (float)gsum16i(nib_dot(PU, CU));                \
            const float c2 = __shfl(sd.x, base + (SIDESL), 64);                \
            const float sc = __shfl(sd.z, base + (SIDESL), 64);                \
            const float dot = draw * (SP) * sc;                                \
            const float num = 2.f * (dot - (P2));                              \
            const float d2  = fmaxf(c2 + (P2) - 2.f * dot, 0.f);               \
            const float den = 2.f * (NP) * sqrtf(d2) + EPSF;                   \
            const float ca  = fminf(fmaxf(num / den, -1.f + EPSF), 1.f - EPSF);\
            my_ca = (sl == (PARKSL)) ? ca : my_ca;                             \
        }
        CONE_STEP(0,  1,  puA, cuA0, p2A, spA, npA)
        CONE_STEP(1,  2,  puA, cuA1, p2A, spA, npA)
        CONE_STEP(2,  3,  puA, cuA2, p2A, spA, npA)
        CONE_STEP(3,  4,  puA, cuA3, p2A, spA, npA)
        CONE_STEP(4,  5,  puA, cuA4, p2A, spA, npA)
        CONE_STEP(8,  9,  puB, cuB0, p2B, spB, npB)
        CONE_STEP(9,  10, puB, cuB1, p2B, spB, npB)
        CONE_STEP(10, 11, puB, cuB2, p2B, spB, npB)
        CONE_STEP(11, 12, puB, cuB3, p2B, spB, npB)
        CONE_STEP(12, 13, puB, cuB4, p2B, spB, npB)
#undef CONE_STEP

        // ONE wave-wide acos covers all parked values.
        const float ap  = (sl < 8) ? apA : apB;
        const float ang = acosf(my_ca);
        const float e   = fmaxf(ang - ap, 0.f);
        const bool pos_ok = (sl == 0) || (validB && sl == 8);
        const bool neg_ok = (sl >= 1 && sl <= 4) || (validB && sl >= 9 && sl <= 12);
        pos_e = gsum16(pos_ok ? e : 0.f);
        neg_e = gsum16(neg_ok ? fmaxf(MARGIN - e, 0.f) : 0.f);
    }

    __shared__ float spos[16], sneg[16];
    if (sl == 0) { spos[wid * 4 + sub] = pos_e; sneg[wid * 4 + sub] = neg_e; }
    __syncthreads();
    if (threadIdx.x == 0) {
        float ps = 0.f, ns = 0.f;
        #pragma unroll
        for (int i = 0; i < 16; ++i) { ps += spos[i]; ns += sneg[i]; }
        part[2 * blockIdx.x]     = ps;
        part[2 * blockIdx.x + 1] = ns;
    }
}

// ---- fp32 fallback (R2 kernel) if ws can't hold the tables ----
__global__ __launch_bounds__(256) void cone_main_f32(
    const float* __restrict__ proto,
    const int*   __restrict__ pairs,
    const int*   __restrict__ negc,
    float*       __restrict__ part,
    int P)
{
    const int lane = threadIdx.x & 63;
    const int wid  = threadIdx.x >> 6;
    const int sub  = lane >> 4;
    const int sl   = lane & 15;
    const int pair = (blockIdx.x * 4 + wid) * 4 + sub;

    float pos_e = 0.f, neg_e = 0.f;
    if (pair < P) {
        const int pi = pairs[2 * pair];
        const int i0 = pairs[2 * pair + 1];
        const int i1 = negc[4 * pair + 0];
        const int i2 = negc[4 * pair + 1];
        const int i3 = negc[4 * pair + 2];
        const int i4 = negc[4 * pair + 3];

        const float4* prow = (const float4*)(proto + (size_t)pi * 256);
        float4 pv[4];
        #pragma unroll
        for (int r = 0; r < 4; ++r) pv[r] = prow[sl + 16 * r];

        float pp = 0.f;
        #pragma unroll
        for (int r = 0; r < 4; ++r) pp += dot4(pv[r], pv[r]);
        float p2     = gsum16(pp);
        float norm_p = sqrtf(p2);
        float apert  = asinf(fminf(fmaxf(BETA / (norm_p + EPSF), 0.f), 1.f - EPSF));

#define CONE_F32_STEP(J, IDX)                                                 \
        {                                                                     \
            const float4* crow = (const float4*)(proto + (size_t)(IDX) * 256);\
            float cc = 0.f, dd = 0.f;                                         \
            _Pragma("unroll")                                                 \
            for (int r = 0; r < 4; ++r) {                                     \
                float4 c = crow[sl + 16 * r], p = pv[r];                      \
                cc += dot4(c, c);                                             \
                float dx = c.x-p.x, dy = c.y-p.y, dz = c.z-p.z, dw = c.w-p.w; \
                dd += dx*dx + dy*dy + dz*dz + dw*dw;                          \
            }                                                                 \
            float c2 = gsum16(cc);                                            \
            float d2 = gsum16(dd);                                            \
            float num    = c2 - p2 - d2;                                      \
            float den    = 2.f * norm_p * sqrtf(d2) + EPSF;                   \
            float cosang = fminf(fmaxf(num / den, -1.f + EPSF), 1.f - EPSF);  \
            float e      = fmaxf(acosf(cosang) - apert, 0.f);                 \
            if (J == 0) pos_e = e;                                            \
            else        neg_e += fmaxf(MARGIN - e, 0.f);                      \
        }
        CONE_F32_STEP(0, i0)
        CONE_F32_STEP(1, i1)
        CONE_F32_STEP(2, i2)
        CONE_F32_STEP(3, i3)
        CONE_F32_STEP(4, i4)
#undef CONE_F32_STEP
    }

    __shared__ float sp[16], sn[16];
    if (sl == 0) { sp[wid * 4 + sub] = pos_e; sn[wid * 4 + sub] = neg_e; }
    __syncthreads();
    if (threadIdx.x == 0) {
        float ps = 0.f, ns = 0.f;
        #pragma unroll
        for (int i = 0; i < 16; ++i) { ps += sp[i]; ns += sn[i]; }
        part[2 * blockIdx.x]     = ps;
        part[2 * blockIdx.x + 1] = ns;
    }
}

__global__ __launch_bounds__(1024) void cone_final(
    const float* __restrict__ part, float* __restrict__ out, int nblocks, int P)
{
    float ps = 0.f, ns = 0.f;
    for (int i = threadIdx.x; i < nblocks; i += 1024) {
        ps += part[2 * i];
        ns += part[2 * i + 1];
    }
    ps = wave_sum(ps);
    ns = wave_sum(ns);
    const int lane = threadIdx.x & 63, wid = threadIdx.x >> 6;
    __shared__ float sp[16], sn[16];
    if (lane == 0) { sp[wid] = ps; sn[wid] = ns; }
    __syncthreads();
    if (threadIdx.x == 0) {
        float tp = 0.f, tn = 0.f;
        #pragma unroll
        for (int i = 0; i < 16; ++i) { tp += sp[i]; tn += sn[i]; }
        float fP = (float)P;
        out[0] = (tp / fP + tn / (fP * (float)KNEG)) * 0.5f;
    }
}

extern "C" void kernel_launch(void* const* d_in, const int* in_sizes, int n_in,
                              void* d_out, int out_size, void* d_ws, size_t ws_size,
                              hipStream_t stream) {
    const float* proto = (const float*)d_in[0];
    const int*   pairs = (const int*)d_in[1];
    const int*   negc  = (const int*)d_in[2];
    const int P = in_sizes[1] / 2;
    const int C = in_sizes[0] / 256;

    const int nblocks_i4  = (P + 31) / 32;   // 2 pairs per 16-lane group
    const int nblocks_f32 = (P + 15) / 16;

    const size_t tab_bytes  = (size_t)C * 128;
    const size_t side_bytes = (size_t)C * 16;
    const size_t part_bytes = (size_t)nblocks_i4 * 2 * sizeof(float);
    const size_t need = tab_bytes + side_bytes + part_bytes;

    if (ws_size >= need) {
        char* base = (char*)d_ws;
        uint2*  tab  = (uint2*)base;
        float4* side = (float4*)(base + tab_bytes);
        float*  part = (float*)(base + tab_bytes + side_bytes);

        cvt_i4<<<(C + 15) / 16, 256, 0, stream>>>(proto, tab, side, C);
        cone_main_i4<<<nblocks_i4, 256, 0, stream>>>(tab, side, pairs, negc, part, P);
        cone_final<<<1, 1024, 0, stream>>>(part, (float*)d_out, nblocks_i4, P);
    } else {
        float* part = (float*)d_ws;
        cone_main_f32<<<nblocks_f32, 256, 0, stream>>>(proto, pairs, negc, part, P);
        cone_final<<<1, 1024, 0, stream>>>(part, (float*)d_out, nblocks_f32, P);
    }
}

// Round 4
// 164.171 us; speedup vs baseline: 1.9024x; 1.0248x over previous
//
#include <hip/hip_runtime.h>

#define BETA   0.1f
#define MARGIN 0.1f
#define EPSF   1e-6f
#define KNEG   4

__device__ __forceinline__ float gsum16(float v) {
    #pragma unroll
    for (int off = 8; off >= 1; off >>= 1) v += __shfl_xor(v, off, 64);
    return v;
}
__device__ __forceinline__ float gmax16(float v) {
    #pragma unroll
    for (int off = 8; off >= 1; off >>= 1) v = fmaxf(v, __shfl_xor(v, off, 64));
    return v;
}
__device__ __forceinline__ float gsum8(float v) {
    #pragma unroll
    for (int off = 4; off >= 1; off >>= 1) v += __shfl_xor(v, off, 64);
    return v;
}
__device__ __forceinline__ int gsum8i(int v) {
    #pragma unroll
    for (int off = 4; off >= 1; off >>= 1) v += __shfl_xor(v, off, 64);
    return v;
}
__device__ __forceinline__ float wave_sum(float v) {
    #pragma unroll
    for (int off = 32; off >= 1; off >>= 1) v += __shfl_xor(v, off, 64);
    return v;
}
__device__ __forceinline__ float dot4(float4 a, float4 b) {
    return a.x*b.x + a.y*b.y + a.z*b.z + a.w*b.w;
}

// ---- pass 1: SIGNED int4 table (128 B/row) + side {norm2, aperture, scale} ----
// Element->nibble mapping is PERMUTED for coalescing: lane sl packs float4s
// {sl, sl+16, sl+32, sl+48} of the row (per-instruction contiguous 256 B per
// 16-lane group). Dots/norms are permutation-invariant since every row uses
// the same mapping. Byte layout in tab is what cone_main_i4 re-reads as uint4;
// only positional correspondence between rows matters, which holds.
__global__ __launch_bounds__(256) void cvt_i4(
    const float* __restrict__ in, uint2* __restrict__ tab,
    float4* __restrict__ side, int C)
{
    const int sl  = threadIdx.x & 15;
    const int row = (blockIdx.x * 256 + threadIdx.x) >> 4;
    if (row >= C) return;
    const float4* src = (const float4*)(in + (size_t)row * 256);
    float4 v0 = src[sl +  0], v1 = src[sl + 16], v2 = src[sl + 32], v3 = src[sl + 48];
    float f[16] = { v0.x, v0.y, v0.z, v0.w,  v1.x, v1.y, v1.z, v1.w,
                    v2.x, v2.y, v2.z, v2.w,  v3.x, v3.y, v3.z, v3.w };
    float am = 0.f;
    #pragma unroll
    for (int d = 0; d < 16; ++d) am = fmaxf(am, fabsf(f[d]));
    am = gmax16(am);
    const float inv = (am > 0.f) ? (7.0f / am) : 0.f;
    unsigned u0 = 0, u1 = 0;
    #pragma unroll
    for (int n = 0; n < 8; ++n) {
        int c = (int)rintf(f[n] * inv);
        c = (c < -8) ? -8 : ((c > 7) ? 7 : c);
        u0 |= ((unsigned)c & 0xFu) << (4 * n);      // two's-complement nibble
    }
    #pragma unroll
    for (int n = 0; n < 8; ++n) {
        int c = (int)rintf(f[8 + n] * inv);
        c = (c < -8) ? -8 : ((c > 7) ? 7 : c);
        u1 |= ((unsigned)c & 0xFu) << (4 * n);
    }
    tab[(size_t)row * 16 + sl] = make_uint2(u0, u1);
    float ss = gsum16(dot4(v0,v0) + dot4(v1,v1) + dot4(v2,v2) + dot4(v3,v3));
    if (sl == 0) {
        float np = sqrtf(ss);
        float ap = asinf(fminf(fmaxf(BETA / (np + EPSF), 0.f), 1.f - EPSF));
        side[row] = make_float4(ss, ap, am * (1.f / 7.0f), 0.f);
    }
}

// Signed-nibble dot of 32 elems/lane: 4 x v_dot8_i32_i4 if available.
__device__ __forceinline__ int nib_dot4(uint4 a, uint4 b) {
#if __has_builtin(__builtin_amdgcn_sdot8)
    int d = __builtin_amdgcn_sdot8((int)a.x, (int)b.x, 0, false);
    d     = __builtin_amdgcn_sdot8((int)a.y, (int)b.y, d, false);
    d     = __builtin_amdgcn_sdot8((int)a.z, (int)b.z, d, false);
    return  __builtin_amdgcn_sdot8((int)a.w, (int)b.w, d, false);
#else
    int acc = 0;
    const unsigned aw[4] = {a.x, a.y, a.z, a.w};
    const unsigned bw[4] = {b.x, b.y, b.z, b.w};
    #pragma unroll
    for (int w = 0; w < 4; ++w)
        #pragma unroll
        for (int n = 0; n < 8; ++n) {
            int pa = ((int)(aw[w] << (28 - 4*n))) >> 28;
            int pb = ((int)(bw[w] << (28 - 4*n))) >> 28;
            acc += pa * pb;
        }
    return acc;
#endif
}

// ---- pass 2: gather + energy. EIGHT-lane groups, uint4 (16 B/lane) row
// reads: one pair per group, 8 pairs per wave, only 9 VMEM instructions per
// wave (6 tab + 1 side + 2 index) vs 16 before — half the issue/TA overhead
// for identical cache-line traffic. Dot reduce is 3 shuffles (gsum8).
// The 5 acos args per pair park on group lanes 0-4; ONE wave-wide acosf
// covers all 40. Block partials go to part[]; cone_final reduces.
__global__ __launch_bounds__(256) void cone_main_i4(
    const uint4*  __restrict__ tab,     // row = 8 x uint4 = 128 B
    const float4* __restrict__ side,
    const int2*   __restrict__ pairs2,
    const int4*   __restrict__ negc4,
    float*        __restrict__ part,
    int P)
{
    const int lane = threadIdx.x & 63;
    const int wid  = threadIdx.x >> 6;
    const int grp  = lane >> 3;          // 8 groups/wave
    const int sl   = lane & 7;
    const int pair = (blockIdx.x * 4 + wid) * 8 + grp;

    float pos_e = 0.f, neg_e = 0.f;
    if (pair < P) {
        const int2 pp = pairs2[pair];    // 8-lane broadcast, 64 B/wave contig
        const int4 nn = negc4[pair];     // 128 B/wave contig
        const int pi = pp.x, i0 = pp.y;

        // Issue ALL table loads (6 rows x 8 lanes x 16 B) before compute.
        uint4 pu  = tab[(size_t)pi   * 8 + sl];
        uint4 cu0 = tab[(size_t)i0   * 8 + sl];
        uint4 cu1 = tab[(size_t)nn.x * 8 + sl];
        uint4 cu2 = tab[(size_t)nn.y * 8 + sl];
        uint4 cu3 = tab[(size_t)nn.z * 8 + sl];
        uint4 cu4 = tab[(size_t)nn.w * 8 + sl];

        // Side gather: lanes 0-5 -> {p, c0..c4}.
        int tidx = pi;
        tidx = (sl == 1) ? i0   : tidx;
        tidx = (sl == 2) ? nn.x : tidx;
        tidx = (sl == 3) ? nn.y : tidx;
        tidx = (sl == 4) ? nn.z : tidx;
        tidx = (sl == 5) ? nn.w : tidx;
        float4 sd = side[tidx];

        const int base = grp * 8;
        const float p2 = __shfl(sd.x, base + 0, 64);
        const float ap = __shfl(sd.y, base + 0, 64);
        const float sp = __shfl(sd.z, base + 0, 64);
        const float np = sqrtf(p2);

        float my_ca = 1.f;   // park acos args; acos(1)=0 on idle lanes

#define CONE_STEP(J, CU)                                                       \
        {                                                                      \
            const float draw = (float)gsum8i(nib_dot4(pu, CU));                \
            const float c2 = __shfl(sd.x, base + 1 + (J), 64);                 \
            const float sc = __shfl(sd.z, base + 1 + (J), 64);                 \
            const float dot = draw * sp * sc;                                  \
            const float num = 2.f * (dot - p2);                                \
            const float d2  = fmaxf(c2 + p2 - 2.f * dot, 0.f);                 \
            const float den = 2.f * np * sqrtf(d2) + EPSF;                     \
            const float ca  = fminf(fmaxf(num / den, -1.f + EPSF), 1.f - EPSF);\
            my_ca = (sl == (J)) ? ca : my_ca;                                  \
        }
        CONE_STEP(0, cu0)
        CONE_STEP(1, cu1)
        CONE_STEP(2, cu2)
        CONE_STEP(3, cu3)
        CONE_STEP(4, cu4)
#undef CONE_STEP

        // ONE wave-wide acos covers all parked values (8 pairs x 5).
        const float ang = acosf(my_ca);
        const float e   = fmaxf(ang - ap, 0.f);
        pos_e = gsum8((sl == 0) ? e : 0.f);
        neg_e = gsum8((sl >= 1 && sl <= 4) ? fmaxf(MARGIN - e, 0.f) : 0.f);
    }

    __shared__ float spos[32], sneg[32];
    if (sl == 0) { spos[wid * 8 + grp] = pos_e; sneg[wid * 8 + grp] = neg_e; }
    __syncthreads();
    if (threadIdx.x == 0) {
        float ps = 0.f, ns = 0.f;
        #pragma unroll
        for (int i = 0; i < 32; ++i) { ps += spos[i]; ns += sneg[i]; }
        part[2 * blockIdx.x]     = ps;
        part[2 * blockIdx.x + 1] = ns;
    }
}

// ---- fp32 fallback if ws can't hold the tables ----
__global__ __launch_bounds__(256) void cone_main_f32(
    const float* __restrict__ proto,
    const int*   __restrict__ pairs,
    const int*   __restrict__ negc,
    float*       __restrict__ part,
    int P)
{
    const int lane = threadIdx.x & 63;
    const int wid  = threadIdx.x >> 6;
    const int sub  = lane >> 4;
    const int sl   = lane & 15;
    const int pair = (blockIdx.x * 4 + wid) * 4 + sub;

    float pos_e = 0.f, neg_e = 0.f;
    if (pair < P) {
        const int pi = pairs[2 * pair];
        const int i0 = pairs[2 * pair + 1];
        const int i1 = negc[4 * pair + 0];
        const int i2 = negc[4 * pair + 1];
        const int i3 = negc[4 * pair + 2];
        const int i4 = negc[4 * pair + 3];

        const float4* prow = (const float4*)(proto + (size_t)pi * 256);
        float4 pv[4];
        #pragma unroll
        for (int r = 0; r < 4; ++r) pv[r] = prow[sl + 16 * r];

        float pp = 0.f;
        #pragma unroll
        for (int r = 0; r < 4; ++r) pp += dot4(pv[r], pv[r]);
        float p2     = gsum16(pp);
        float norm_p = sqrtf(p2);
        float apert  = asinf(fminf(fmaxf(BETA / (norm_p + EPSF), 0.f), 1.f - EPSF));

#define CONE_F32_STEP(J, IDX)                                                 \
        {                                                                     \
            const float4* crow = (const float4*)(proto + (size_t)(IDX) * 256);\
            float cc = 0.f, dd = 0.f;                                         \
            _Pragma("unroll")                                                 \
            for (int r = 0; r < 4; ++r) {                                     \
                float4 c = crow[sl + 16 * r], p = pv[r];                      \
                cc += dot4(c, c);                                             \
                float dx = c.x-p.x, dy = c.y-p.y, dz = c.z-p.z, dw = c.w-p.w; \
                dd += dx*dx + dy*dy + dz*dz + dw*dw;                          \
            }                                                                 \
            float c2 = gsum16(cc);                                            \
            float d2 = gsum16(dd);                                            \
            float num    = c2 - p2 - d2;                                      \
            float den    = 2.f * norm_p * sqrtf(d2) + EPSF;                   \
            float cosang = fminf(fmaxf(num / den, -1.f + EPSF), 1.f - EPSF);  \
            float e      = fmaxf(acosf(cosang) - apert, 0.f);                 \
            if (J == 0) pos_e = e;                                            \
            else        neg_e += fmaxf(MARGIN - e, 0.f);                      \
        }
        CONE_F32_STEP(0, i0)
        CONE_F32_STEP(1, i1)
        CONE_F32_STEP(2, i2)
        CONE_F32_STEP(3, i3)
        CONE_F32_STEP(4, i4)
#undef CONE_F32_STEP
    }

    __shared__ float sp[16], sn[16];
    if (sl == 0) { sp[wid * 4 + sub] = pos_e; sn[wid * 4 + sub] = neg_e; }
    __syncthreads();
    if (threadIdx.x == 0) {
        float ps = 0.f, ns = 0.f;
        #pragma unroll
        for (int i = 0; i < 16; ++i) { ps += sp[i]; ns += sn[i]; }
        part[2 * blockIdx.x]     = ps;
        part[2 * blockIdx.x + 1] = ns;
    }
}

__global__ __launch_bounds__(1024) void cone_final(
    const float* __restrict__ part, float* __restrict__ out, int nblocks, int P)
{
    float ps = 0.f, ns = 0.f;
    for (int i = threadIdx.x; i < nblocks; i += 1024) {
        ps += part[2 * i];
        ns += part[2 * i + 1];
    }
    ps = wave_sum(ps);
    ns = wave_sum(ns);
    const int lane = threadIdx.x & 63, wid = threadIdx.x >> 6;
    __shared__ float sp[16], sn[16];
    if (lane == 0) { sp[wid] = ps; sn[wid] = ns; }
    __syncthreads();
    if (threadIdx.x == 0) {
        float tp = 0.f, tn = 0.f;
        #pragma unroll
        for (int i = 0; i < 16; ++i) { tp += sp[i]; tn += sn[i]; }
        float fP = (float)P;
        out[0] = (tp / fP + tn / (fP * (float)KNEG)) * 0.5f;
    }
}

extern "C" void kernel_launch(void* const* d_in, const int* in_sizes, int n_in,
                              void* d_out, int out_size, void* d_ws, size_t ws_size,
                              hipStream_t stream) {
    const float* proto = (const float*)d_in[0];
    const int*   pairs = (const int*)d_in[1];
    const int*   negc  = (const int*)d_in[2];
    const int P = in_sizes[1] / 2;
    const int C = in_sizes[0] / 256;

    const int nblocks_i4  = (P + 31) / 32;   // 32 pairs per block (8/wave)
    const int nblocks_f32 = (P + 15) / 16;

    const size_t tab_bytes  = (size_t)C * 128;
    const size_t side_bytes = (size_t)C * 16;
    const size_t part_bytes = (size_t)nblocks_i4 * 2 * sizeof(float);
    const size_t need = tab_bytes + side_bytes + part_bytes;

    if (ws_size >= need) {
        char* base = (char*)d_ws;
        uint2*  tab  = (uint2*)base;
        float4* side = (float4*)(base + tab_bytes);
        float*  part = (float*)(base + tab_bytes + side_bytes);

        cvt_i4<<<(C + 15) / 16, 256, 0, stream>>>(proto, tab, side, C);
        cone_main_i4<<<nblocks_i4, 256, 0, stream>>>((const uint4*)tab, side,
                                                     (const int2*)pairs,
                                                     (const int4*)negc, part, P);
        cone_final<<<1, 1024, 0, stream>>>(part, (float*)d_out, nblocks_i4, P);
    } else {
        float* part = (float*)d_ws;
        cone_main_f32<<<nblocks_f32, 256, 0, stream>>>(proto, pairs, negc, part, P);
        cone_final<<<1, 1024, 0, stream>>>(part, (float*)d_out, nblocks_f32, P);
    }
}